// Round 6
// baseline (731.242 us; speedup 1.0000x reference)
//
#include <hip/hip_runtime.h>
#include <hip/hip_bf16.h>
#include <math.h>

#define NB 64
#define PP 7

typedef __attribute__((ext_vector_type(8))) short short8;
typedef __attribute__((ext_vector_type(4))) float f32x4;

// round-to-nearest-even bf16 from f32, packed pair -> u32 (lo=a, hi=b)
static __device__ inline unsigned bf16r(float f) {
    unsigned u = __builtin_bit_cast(unsigned, f);
    u += 0x7fffu + ((u >> 16) & 1u);
    return u >> 16;
}
static __device__ inline unsigned pack2(float a, float b) {
    return bf16r(a) | (bf16r(b) << 16);
}

// ---------------------------------------------------------------------------
// crop: GRP lanes per (n,c) plane, VEC columns per lane (float4/float2).
// Running column cumsum; capture at patch row boundaries; x-mask + xor-tree
// reduce within GRP-aligned lane group. No LDS, no barriers.
// ---------------------------------------------------------------------------
template<int H, int VEC, int GRP>
__global__ __launch_bounds__(256) void crop_kernel(
    const float* __restrict__ x, const int* __restrict__ patchs,
    float* __restrict__ out, int C, int num, int den, int ldo, int col0)
{
    constexpr int USED = H / VEC;        // active lanes per plane
    constexpr int PPWAVE = 64 / GRP;     // planes per wave
    int tid = threadIdx.x, lane = tid & 63, wv = tid >> 6;
    int n = blockIdx.y;
    int sub = lane / GRP, xl = lane & (GRP - 1);
    bool act = xl < USED;
    int c = blockIdx.x * (4 * PPWAVE) + wv * PPWAVE + sub;

    int y0m1[PP], y1s[PP], x0s[PP], x1s[PP], zer[PP];
    float rarea[PP];
    #pragma unroll
    for (int p = 0; p < PP; ++p) {
        int p0 = patchs[(n * PP + p) * 4 + 0];
        int p1 = patchs[(n * PP + p) * 4 + 1];
        int p2 = patchs[(n * PP + p) * 4 + 2];
        int p3 = patchs[(n * PP + p) * 4 + 3];
        int y0 = p0 * num / den, y1 = p1 * num / den;
        int xx0 = p2 * num / den, xx1 = p3 * num / den;
        y0m1[p] = y0 - 1; y1s[p] = y1; x0s[p] = xx0; x1s[p] = xx1;
        rarea[p] = 1.f / (float)((y1 - y0 + 1) * (xx1 - xx0 + 1));
        zer[p] = (p0 | p1 | p2 | p3) == 0;
    }

    const float* pl = x + ((size_t)n * C + c) * (H * H) + (act ? xl * VEC : 0);

    float cc[VEC];
    float lo[PP][VEC], hi[PP][VEC];
    #pragma unroll
    for (int e = 0; e < VEC; ++e) cc[e] = 0.f;
    #pragma unroll
    for (int p = 0; p < PP; ++p)
        #pragma unroll
        for (int e = 0; e < VEC; ++e) { lo[p][e] = 0.f; hi[p][e] = 0.f; }

    #pragma unroll 4
    for (int y = 0; y < H; ++y) {
        float v[VEC];
        if constexpr (VEC == 4) {
            float4 t = *reinterpret_cast<const float4*>(pl + y * H);
            v[0] = t.x; v[1] = t.y; v[2] = t.z; v[3] = t.w;
        } else {
            float2 t = *reinterpret_cast<const float2*>(pl + y * H);
            v[0] = t.x; v[1] = t.y;
        }
        #pragma unroll
        for (int e = 0; e < VEC; ++e) cc[e] += v[e];
        #pragma unroll
        for (int p = 0; p < PP; ++p) {
            #pragma unroll
            for (int e = 0; e < VEC; ++e) {
                lo[p][e] = (y == y0m1[p]) ? cc[e] : lo[p][e];
                hi[p][e] = (y == y1s[p]) ? cc[e] : hi[p][e];
            }
        }
    }

    #pragma unroll
    for (int p = 0; p < PP; ++p) {
        float d = 0.f;
        #pragma unroll
        for (int e = 0; e < VEC; ++e) {
            int col = xl * VEC + e;
            if (col >= x0s[p] && col <= x1s[p]) d += hi[p][e] - lo[p][e];
        }
        #pragma unroll
        for (int off = GRP / 2; off >= 1; off >>= 1)
            d += __shfl_xor(d, off, 64);
        if (act && xl == 0)
            out[(size_t)(n * PP + p) * ldo + col0 + c] = zer[p] ? 0.f : d * rarea[p];
    }
}

// ---------------------------------------------------------------------------
// bf16 MFMA gemm, 64x64 tile. C[m,o] = sum_k X[m,k]*W[o,k].
// X:[M,ldx] f32, W:[O,K] f32 row-major, converted bf16 during staging.
// 256 thr = 4 waves; wave w -> cols [16w,16w+16). grid=(O/64, M/64, S).
// split-K chunk kchunk (mult of 64). partial: raw acc -> out + z*M*ldo.
// ---------------------------------------------------------------------------
__global__ __launch_bounds__(256) void gemm64_kernel(
    const float* __restrict__ X, int ldx,
    const float* __restrict__ W, int K,
    const float* __restrict__ bias,
    float* __restrict__ out, int ldo,
    int kchunk, int partial)
{
    __shared__ short Xs[64][72];
    __shared__ short Ws[64][72];
    int tid = threadIdx.x;
    int lane = tid & 63, wv = tid >> 6;
    int m0 = blockIdx.y * 64;
    int o0 = blockIdx.x * 64;
    int z = blockIdx.z;
    int kbeg = z * kchunk, kend = kbeg + kchunk;

    f32x4 acc[4];
    #pragma unroll
    for (int i = 0; i < 4; ++i) acc[i] = (f32x4){0.f, 0.f, 0.f, 0.f};

    for (int kb = kbeg; kb < kend; kb += 64) {
        #pragma unroll
        for (int i = 0; i < 2; ++i) {
            int cch = tid + 256 * i;
            int r = cch >> 3, col = (cch & 7) * 8;
            const float* src = X + (size_t)(m0 + r) * ldx + kb + col;
            float4 a = *reinterpret_cast<const float4*>(src);
            float4 b = *reinterpret_cast<const float4*>(src + 4);
            uint4 v;
            v.x = pack2(a.x, a.y); v.y = pack2(a.z, a.w);
            v.z = pack2(b.x, b.y); v.w = pack2(b.z, b.w);
            *reinterpret_cast<uint4*>(&Xs[r][col]) = v;
            const float* srcw = W + (size_t)(o0 + r) * K + kb + col;
            float4 c = *reinterpret_cast<const float4*>(srcw);
            float4 d = *reinterpret_cast<const float4*>(srcw + 4);
            uint4 w;
            w.x = pack2(c.x, c.y); w.y = pack2(c.z, c.w);
            w.z = pack2(d.x, d.y); w.w = pack2(d.z, d.w);
            *reinterpret_cast<uint4*>(&Ws[r][col]) = w;
        }
        __syncthreads();
        #pragma unroll
        for (int kk = 0; kk < 64; kk += 32) {
            int ro = lane & 15, kof = kk + (lane >> 4) * 8;
            short8 b = *reinterpret_cast<const short8*>(&Ws[wv * 16 + ro][kof]);
            #pragma unroll
            for (int i = 0; i < 4; ++i) {
                short8 a = *reinterpret_cast<const short8*>(&Xs[16 * i + ro][kof]);
                acc[i] = __builtin_amdgcn_mfma_f32_16x16x32_bf16(a, b, acc[i], 0, 0, 0);
            }
        }
        __syncthreads();
    }

    float* dst = out;
    if (partial) dst += (size_t)z * (gridDim.y * 64) * ldo;
    int o = o0 + wv * 16 + (lane & 15);
    float bv = (!partial && bias) ? bias[o] : 0.f;
    int mr = (lane >> 4) * 4;
    #pragma unroll
    for (int i = 0; i < 4; ++i) {
        #pragma unroll
        for (int r = 0; r < 4; ++r) {
            int m = m0 + 16 * i + mr + r;
            dst[(size_t)m * ldo + o] = acc[i][r] + bv;
        }
    }
}

// ---------------------------------------------------------------------------
// Fused LSTM step: gates gemm (h_prev @ whh^T) + xg add + cell, one kernel.
// Block b owns hidden units j in [16b,16b+16): computes ALL 4 gate types for
// those units (wave w = gate type w, whh rows g*H + 16b + jj gathered in
// staging), exchanges gates via LDS, then cell for (n=64, j=16).
// h ping-pong: reads hprev (all columns), writes hnew (own columns only).
// c is column-partitioned -> in-place safe. first=1: gates = xg only, c=0.
// grid = H/16 blocks.
// ---------------------------------------------------------------------------
__global__ __launch_bounds__(256) void lstm_step_kernel(
    const float* __restrict__ hprev, const float* __restrict__ whh,
    const float* __restrict__ xgt, int ldxg,
    float* __restrict__ hnew, float* __restrict__ c,
    float* __restrict__ dest, int ldd, int H, int first)
{
    __shared__ short Hs[64][72];
    __shared__ short Ws[64][72];
    __shared__ float gbuf[4][64][20];
    int tid = threadIdx.x, lane = tid & 63, wv = tid >> 6;
    int j0 = blockIdx.x * 16;

    if (!first) {
        f32x4 acc[4];
        #pragma unroll
        for (int i = 0; i < 4; ++i) acc[i] = (f32x4){0.f, 0.f, 0.f, 0.f};
        for (int kb = 0; kb < H; kb += 64) {
            #pragma unroll
            for (int i = 0; i < 2; ++i) {
                int cch = tid + 256 * i;
                int r = cch >> 3, col = (cch & 7) * 8;
                const float* src = hprev + (size_t)r * H + kb + col;
                float4 a = *reinterpret_cast<const float4*>(src);
                float4 bb = *reinterpret_cast<const float4*>(src + 4);
                uint4 v;
                v.x = pack2(a.x, a.y); v.y = pack2(a.z, a.w);
                v.z = pack2(bb.x, bb.y); v.w = pack2(bb.z, bb.w);
                *reinterpret_cast<uint4*>(&Hs[r][col]) = v;
                int wr = (r >> 4) * H + j0 + (r & 15);
                const float* srcw = whh + (size_t)wr * H + kb + col;
                float4 cc = *reinterpret_cast<const float4*>(srcw);
                float4 dd = *reinterpret_cast<const float4*>(srcw + 4);
                uint4 w;
                w.x = pack2(cc.x, cc.y); w.y = pack2(cc.z, cc.w);
                w.z = pack2(dd.x, dd.y); w.w = pack2(dd.z, dd.w);
                *reinterpret_cast<uint4*>(&Ws[r][col]) = w;
            }
            __syncthreads();
            #pragma unroll
            for (int kk = 0; kk < 64; kk += 32) {
                int ro = lane & 15, kof = kk + (lane >> 4) * 8;
                short8 b = *reinterpret_cast<const short8*>(&Ws[wv * 16 + ro][kof]);
                #pragma unroll
                for (int i = 0; i < 4; ++i) {
                    short8 a = *reinterpret_cast<const short8*>(&Hs[16 * i + ro][kof]);
                    acc[i] = __builtin_amdgcn_mfma_f32_16x16x32_bf16(a, b, acc[i], 0, 0, 0);
                }
            }
            __syncthreads();
        }
        int mr = (lane >> 4) * 4, jj = lane & 15;
        #pragma unroll
        for (int i = 0; i < 4; ++i)
            #pragma unroll
            for (int r = 0; r < 4; ++r)
                gbuf[wv][16 * i + mr + r][jj] = acc[i][r];
        __syncthreads();
    }

    // cell: thread -> n = tid>>2, 4 consecutive j at jq
    int n = tid >> 2, jq = (tid & 3) * 4;
    f32x4 g[4];
    #pragma unroll
    for (int gi = 0; gi < 4; ++gi) {
        g[gi] = *reinterpret_cast<const f32x4*>(&xgt[(size_t)n * ldxg + gi * H + j0 + jq]);
        if (!first) g[gi] += *reinterpret_cast<const f32x4*>(&gbuf[gi][n][jq]);
    }
    f32x4 cp = (f32x4){0.f, 0.f, 0.f, 0.f};
    if (!first) cp = *reinterpret_cast<const f32x4*>(&c[(size_t)n * H + j0 + jq]);
    f32x4 cn, hn;
    #pragma unroll
    for (int k = 0; k < 4; ++k) {
        float si = 1.f / (1.f + expf(-g[0][k]));
        float sf = 1.f / (1.f + expf(-g[1][k]));
        float so = 1.f / (1.f + expf(-g[3][k]));
        float ccv = sf * cp[k] + si * tanhf(g[2][k]);
        cn[k] = ccv;
        hn[k] = so * tanhf(ccv);
    }
    *reinterpret_cast<f32x4*>(&c[(size_t)n * H + j0 + jq]) = cn;
    *reinterpret_cast<f32x4*>(&hnew[(size_t)n * H + j0 + jq]) = hn;
    *reinterpret_cast<f32x4*>(&dest[(size_t)n * ldd + j0 + jq]) = hn;
}

// ---------------------------------------------------------------------------
// reduce split-K partials: out[m*O+o] = act(sum_s partial[s][m][o] + bias[o])
// ---------------------------------------------------------------------------
__global__ __launch_bounds__(256) void reduce_kernel(
    const float* __restrict__ partial, int S, int M, int O,
    const float* __restrict__ bias, int relu, float* __restrict__ out)
{
    int idx = blockIdx.x * 256 + threadIdx.x;
    int tot = M * O;
    if (idx >= tot) return;
    float v = bias[idx % O];
    for (int s = 0; s < S; ++s) v += partial[(size_t)s * tot + idx];
    if (relu) v = fmaxf(v, 0.f);
    out[idx] = v;
}

// ---------------------------------------------------------------------------
// fused attn logits + softmax + weighted pool: feat[n,:] = sum_p alpha_p rnn3
// ---------------------------------------------------------------------------
__global__ __launch_bounds__(256) void attn_fused_kernel(
    const float* __restrict__ h2, const float* __restrict__ aw3,
    const float* __restrict__ ab3, const float* __restrict__ rnn3,
    float* __restrict__ feat)
{
    int n = blockIdx.x;
    int tid = threadIdx.x, lane = tid & 63, wv = tid >> 6;
    __shared__ float logit[PP];
    __shared__ float alpha[PP];
    for (int p = wv; p < PP; p += 4) {
        float s = 0.f;
        for (int k = lane; k < 1792; k += 64)
            s += h2[n * 1792 + k] * aw3[p * 1792 + k];
        #pragma unroll
        for (int off = 32; off; off >>= 1) s += __shfl_down(s, off, 64);
        if (lane == 0) logit[p] = fmaxf(s + ab3[p], 0.f);
    }
    __syncthreads();
    if (tid == 0) {
        float a[PP], mx = -1e30f;
        for (int p = 0; p < PP; ++p) { a[p] = logit[p]; mx = fmaxf(mx, a[p]); }
        float s = 0.f;
        for (int p = 0; p < PP; ++p) { a[p] = expf(a[p] - mx); s += a[p]; }
        for (int p = 0; p < PP; ++p) alpha[p] = a[p] / s;
    }
    __syncthreads();
    for (int j = tid; j < 1792; j += 256) {
        float s = 0.f;
        #pragma unroll
        for (int p = 0; p < PP; ++p)
            s += rnn3[((size_t)n * PP + p) * 1792 + j] * alpha[p];
        feat[(size_t)n * 1792 + j] = s;
    }
}

// ---------------------------------------------------------------------------

extern "C" void kernel_launch(void* const* d_in, const int* in_sizes, int n_in,
                              void* d_out, int out_size, void* d_ws, size_t ws_size,
                              hipStream_t stream) {
    const float* x1 = (const float*)d_in[0];
    const float* x2 = (const float*)d_in[1];
    const float* x3 = (const float*)d_in[2];
    const int* patchs = (const int*)d_in[3];
    const float* l1_wih = (const float*)d_in[4];
    const float* l1_whh = (const float*)d_in[5];
    const float* l1_b   = (const float*)d_in[6];
    const float* l2_wih = (const float*)d_in[7];
    const float* l2_whh = (const float*)d_in[8];
    const float* l2_b   = (const float*)d_in[9];
    const float* l3_wih = (const float*)d_in[10];
    const float* l3_whh = (const float*)d_in[11];
    const float* l3_b   = (const float*)d_in[12];
    const float* aw1 = (const float*)d_in[13];
    const float* ab1 = (const float*)d_in[14];
    const float* aw2 = (const float*)d_in[15];
    const float* ab2 = (const float*)d_in[16];
    const float* aw3 = (const float*)d_in[17];
    const float* ab3 = (const float*)d_in[18];
    const float* fw  = (const float*)d_in[19];
    const float* fb  = (const float*)d_in[20];
    float* out = (float*)d_out;

    float* ws = (float*)d_ws;
    float* local1 = ws;                       // [448,256]
    float* local2 = local1 + 114688;          // [448,768]
    float* local3 = local2 + 344064;          // [448,1792]
    float* rnn3   = local3;                   // alias: local3 dead after xg3
    float* xg     = local3 + 802816;          // [448,7168] max
    float* partial= xg + 3211264;             // 1605632 f32 max (aw1 split-7)
    float* hbufA  = partial + 1835008;        // [64,1792]
    float* hbufB  = hbufA + 114688;           // [64,1792]
    float* cbuf   = hbufB + 114688;           // [64,1792]
    float* h1     = cbuf + 114688;            // [64,3584]
    float* h2     = h1 + 229376;              // [64,1792]
    float* feat   = h2 + 114688;              // [64,1792]

    // ---- crops ----
    crop_kernel<56, 4, 16><<<dim3(16, NB), 256, 0, stream>>>(
        x1, patchs, local1, 256, 55, 55, 256, 0);
    crop_kernel<28, 4, 8><<<dim3(16, NB), 256, 0, stream>>>(
        x2, patchs, local2, 512, 27, 55, 768, 0);
    crop_kernel<14, 2, 8><<<dim3(32, NB), 256, 0, stream>>>(
        x3, patchs, local3, 1024, 13, 55, 1792, 0);

    struct LstmCfg {
        const float *Xbuf, *wih, *whh, *b;
        int D, H;
        float* dest_base; int destHT, col0;
    };
    LstmCfg cfgs[3] = {
        { local1, l1_wih, l1_whh, l1_b, 256, 256, local2, 768, 512 },
        { local2, l2_wih, l2_whh, l2_b, 768, 768, local3, 1792, 1024 },
        { local3, l3_wih, l3_whh, l3_b, 1792, 1792, rnn3, 1792, 0 },
    };
    for (int L = 0; L < 3; ++L) {
        LstmCfg& cf = cfgs[L];
        int H4 = 4 * cf.H;
        // xg = X @ wih^T + b : [448, 4H]
        gemm64_kernel<<<dim3(H4 / 64, 7, 1), 256, 0, stream>>>(
            cf.Xbuf, cf.D, cf.wih, cf.D, cf.b, xg, H4, cf.D, 0);
        for (int t = 0; t < PP; ++t) {
            float* hp = (t & 1) ? hbufB : hbufA;
            float* hw = (t & 1) ? hbufA : hbufB;
            float* dest = cf.dest_base + (size_t)t * cf.destHT + cf.col0;
            lstm_step_kernel<<<cf.H / 16, 256, 0, stream>>>(
                hp, cf.whh, xg + (size_t)t * H4, PP * H4,
                hw, cbuf, dest, PP * cf.destHT, cf.H, t == 0);
        }
    }

    // ---- attention MLP ----
    // aw1: [64,12544] x [3584,12544]^T, split-K 7
    gemm64_kernel<<<dim3(56, 1, 7), 256, 0, stream>>>(
        rnn3, 12544, aw1, 12544, nullptr, partial, 3584, 1792, 1);
    reduce_kernel<<<(64 * 3584 + 255) / 256, 256, 0, stream>>>(
        partial, 7, 64, 3584, ab1, 1, h1);
    // aw2: [64,3584] x [1792,3584]^T, split-K 4
    gemm64_kernel<<<dim3(28, 1, 4), 256, 0, stream>>>(
        h1, 3584, aw2, 3584, nullptr, partial, 1792, 896, 1);
    reduce_kernel<<<(64 * 1792 + 255) / 256, 256, 0, stream>>>(
        partial, 4, 64, 1792, ab2, 1, h2);
    attn_fused_kernel<<<NB, 256, 0, stream>>>(h2, aw3, ab3, rnn3, feat);
    // fw: [64,1792] x [512,1792]^T, split-K 7
    gemm64_kernel<<<dim3(8, 1, 7), 256, 0, stream>>>(
        feat, 1792, fw, 1792, nullptr, partial, 512, 256, 1);
    reduce_kernel<<<(64 * 512 + 255) / 256, 256, 0, stream>>>(
        partial, 7, 64, 512, fb, 0, out);
}